// Round 10
// baseline (172.468 us; speedup 1.0000x reference)
//
#include <hip/hip_runtime.h>

#define NS 4096
#define DC 32
#define MAXROUND 210  // 14 sweeps cap
#define CHKIV 8       // gate check every 8 rounds

typedef float v2f __attribute__((ext_vector_type(2)));

static __device__ __forceinline__ v2f vswap(v2f b) {
    return __builtin_shufflevector(b, b, 1, 0);
}

// slot of matrix index r under round-rr pairing (pair k = {(rr+k)%15, (rr+15-k)%15}, p0=15)
static __device__ __forceinline__ int slot_of(int r, int rr) {
    if (r == 15) return 0;
    int m = r - rr; if (m < 0) m += 15;
    if (m == 0) return 1;
    return (m <= 7) ? 2*m : 31 - 2*m;
}
// tournament advance: content at slot s moves to pi_next(s) for the next round
static __device__ __forceinline__ int pi_next(int s) {
    if (s == 0) return 0;
    if (s == 2) return 1;
    if (!(s & 1)) return s - 2;
    return (s == 15) ? 14 : s + 2;
}
// byte address of (row sr, col-slot sc): pair-contiguous, bank-spread swizzle
static __device__ __forceinline__ int laddr(int sr, int sc) {
    return (sr << 7) | ((((sc >> 1) + sr) & 7) << 4) | ((sc & 1) << 3);
}

// ---------------------------------------------------------------------------
// P1 (R1-verbatim) + d_out zeroing.
// ---------------------------------------------------------------------------
__global__ __launch_bounds__(256) void precompute_kernel(
    const float* __restrict__ Ar, const float* __restrict__ Ai,
    float2* __restrict__ S, float2* __restrict__ W,
    float2* __restrict__ cA, float2* __restrict__ cA2,
    float* __restrict__ out)
{
    const int d = blockIdx.x;
    const int t = threadIdx.x;
    if (d == 0 && t == 0) out[0] = 0.f;
    const int i = t >> 4, j = t & 15;
    __shared__ float ar[16][16], ai[16][16], a2r[16][16], a2i[16][16];
    ar[i][j] = Ar[d*256 + t];
    ai[i][j] = Ai[d*256 + t];
    __syncthreads();
    float a2re = 0.f, a2im = 0.f, wre = 0.f, wim = 0.f;
    for (int k = 0; k < 16; ++k) {
        float xr = ar[i][k], xi = ai[i][k];
        a2re += xr*ar[k][j] - xi*ai[k][j];
        a2im += xr*ai[k][j] + xi*ar[k][j];
        wre += xr*ar[j][k] + xi*ai[j][k];
        wim += xi*ar[j][k] - xr*ai[j][k];
    }
    S[d*256 + t] = make_float2(ar[i][j] + ar[j][i], ai[i][j] - ai[j][i]);
    W[d*256 + t] = make_float2(wre, wim);
    a2r[i][j] = a2re; a2i[i][j] = a2im;
    __syncthreads();
    if (t < 16) {
        float sr = 0.f, si = 0.f, s2r = 0.f, s2i = 0.f;
        for (int ii = 0; ii < 16; ++ii) {
            sr  += ar[ii][t];  si  += ai[ii][t];
            s2r += a2r[ii][t]; s2i += a2i[ii][t];
        }
        cA [d*16 + t] = make_float2(sr,  si);
        cA2[d*16 + t] = make_float2(s2r, s2i);
    }
}

// ---------------------------------------------------------------------------
// Slot-indexed quartet Jacobi: static addresses, b128 quartet reads, content
// moves by fixed permutation pi. Coefs from diag quartets via shuffle.
// ---------------------------------------------------------------------------
__global__ __launch_bounds__(64) void energy_kernel(
    const float* __restrict__ X,
    const float2* __restrict__ S, const float2* __restrict__ W,
    const float2* __restrict__ cA, const float2* __restrict__ cA2,
    float* __restrict__ out)
{
    const int n = blockIdx.x;
    const int t = threadIdx.x;
    const int a = t >> 3, b = t & 7;

    __shared__ v2f    H[256], V[256];
    __shared__ float  xS[32];
    __shared__ float  diagS[16];
    __shared__ v2f    psiS[16];
    __shared__ int    midxS;

    const float* Xn = X + n*DC;
    if (t < 32) xS[t] = Xn[t];

    // ---- static addresses (loop-invariant) ----
    const int sr0 = 2*a, sr1 = 2*a + 1;     // H slot-rows == V matrix-rows
    const int sc0 = 2*b, sc1 = 2*b + 1;     // col slots
    const int rd0 = (sr0 << 7) | (((b + sr0) & 7) << 4);   // 16B: (sr0,sc0..sc1)
    const int rd1 = (sr1 << 7) | (((b + sr1) & 7) << 4);
    const int pr0 = pi_next(sr0), pr1 = pi_next(sr1);
    const int pc0 = pi_next(sc0), pc1 = pi_next(sc1);
    const int wH00 = laddr(pr0, pc0), wH01 = laddr(pr0, pc1);
    const int wH10 = laddr(pr1, pc0), wH11 = laddr(pr1, pc1);
    const int wV00 = laddr(sr0, pc0), wV01 = laddr(sr0, pc1);
    const int wV10 = laddr(sr1, pc0), wV11 = laddr(sr1, pc1);
    const int la = a * 9, lb = b * 9;       // diag lanes holding pair coefs
    const bool diagLane = (a == b);

    // ---- build H (R1-exact arithmetic) into slot layout ----
    float tol2;
    {
        const int bi = t >> 2, bj = (t & 3) * 4, e0 = t * 4;
        v2f acc[4] = {{0.f,0.f},{0.f,0.f},{0.f,0.f},{0.f,0.f}};
        float sx2 = 0.f;
        for (int d = 0; d < DC; ++d) {
            float xd = Xn[d];
            sx2 += xd*xd;
            const float4* w4 = (const float4*)(W + d*256 + e0);
            const float4* s4 = (const float4*)(S + d*256 + e0);
            float4 wa = w4[0], wb = w4[1];
            float4 sa = s4[0], sb = s4[1];
            v2f xv = {xd, xd};
            acc[0] += (v2f){wa.x, wa.y} - xv * (v2f){sa.x, sa.y};
            acc[1] += (v2f){wa.z, wa.w} - xv * (v2f){sa.z, sa.w};
            acc[2] += (v2f){wb.x, wb.y} - xv * (v2f){sb.x, sb.y};
            acc[3] += (v2f){wb.z, wb.w} - xv * (v2f){sb.z, sb.w};
        }
        float sdiag = 0.5f*sx2 + 1e-5f;
        float nf = 0.f;
        const int sbi = slot_of(bi, 0);
        #pragma unroll
        for (int u = 0; u < 4; ++u) {
            int j = bj + u;
            v2f hv = 0.5f * acc[u];
            if (bi == j) hv.x += sdiag;
            nf += hv.x*hv.x + hv.y*hv.y;
            const int scj = slot_of(j, 0);
            *(v2f*)((char*)H + laddr(sbi, scj)) = hv;
            *(v2f*)((char*)V + laddr(bi,  scj)) =
                (bi == j) ? (v2f){1.f, 0.f} : (v2f){0.f, 0.f};
        }
        #pragma unroll
        for (int m = 1; m < 64; m <<= 1) nf += __shfl_xor(nf, m);
        tol2 = 1e-10f * nf;
    }
    __syncthreads();

    // ---- round loop ----
    int rr = 0, iter = 0, chkcd = CHKIV;
    for (;;) {
        float4 f0 = *(const float4*)((const char*)H + rd0);
        float4 f1 = *(const float4*)((const char*)H + rd1);
        float4 g0 = *(const float4*)((const char*)V + rd0);
        float4 g1 = *(const float4*)((const char*)V + rd1);
        v2f h11 = {f0.x, f0.y}, h12 = {f0.z, f0.w};
        v2f h21 = {f1.x, f1.y}, h22 = {f1.z, f1.w};
        v2f q11 = {g0.x, g0.y}, q12 = {g0.z, g0.w};
        v2f q21 = {g1.x, g1.y}, q22 = {g1.z, g1.w};

        // coef candidate from own quartet (meaningful on diag lanes only)
        float av = h11.x, dv = h22.x;
        float ab2 = h12.x*h12.x + h12.y*h12.y;
        float c_, s_, er, ei;
        if (ab2 > 1e-60f) {
            float abr = __builtin_amdgcn_rsqf(ab2);
            er = h12.x * abr; ei = h12.y * abr;
            float tau = (dv - av) * (0.5f * abr);
            float den = fabsf(tau) + sqrtf(1.f + tau*tau);
            float tv = __builtin_amdgcn_rcpf(den);
            tv = (tau < 0.f) ? -tv : tv;
            c_ = __builtin_amdgcn_rsqf(1.f + tv*tv);
            s_ = tv * c_;
        } else { c_ = 1.f; s_ = 0.f; er = 1.f; ei = 0.f; }

        const float ca = __shfl(c_, la), sa = __shfl(s_, la);
        const float eax = __shfl(er, la), eay = __shfl(ei, la);
        const float cb = __shfl(c_, lb), sb = __shfl(s_, lb);
        const float ebx = __shfl(er, lb), eby = __shfl(ei, lb);

        // rotation (R9-verbatim math)
        const float sbex = sb*ebx, sbey = sb*eby;
        const float cbex = cb*ebx, cbey = cb*eby;
        const v2f CB  = {cb, cb},      SB  = {sb, sb};
        const v2f P1x = {-sbex,-sbex}, P1y = {-sbey, sbey};
        const v2f Q1x = {cbex, cbex},  Q1y = {cbey,-cbey};
        const float saex = sa*eax, saey = sa*eay;
        const float caex = ca*eax, caey = ca*eay;
        const v2f CA  = {ca, ca},      SA  = {sa, sa};
        const v2f P2x = {-saex,-saex}, P2y = {saey,-saey};
        const v2f Q2x = {caex, caex},  Q2y = {-caey, caey};

        v2f t11 = CB*h11  + P1x*h12 + P1y*vswap(h12);
        v2f t12 = Q1x*h12 + Q1y*vswap(h12) + SB*h11;
        v2f t21 = CB*h21  + P1x*h22 + P1y*vswap(h22);
        v2f t22 = Q1x*h22 + Q1y*vswap(h22) + SB*h21;
        v2f n11 = CA*t11  + P2x*t21 + P2y*vswap(t21);
        v2f n12 = CA*t12  + P2x*t22 + P2y*vswap(t22);
        v2f n21 = Q2x*t21 + Q2y*vswap(t21) + SA*t11;
        v2f n22 = Q2x*t22 + Q2y*vswap(t22) + SA*t12;
        v2f u11 = CB*q11  + P1x*q12 + P1y*vswap(q12);
        v2f u12 = Q1x*q12 + Q1y*vswap(q12) + SB*q11;
        v2f u21 = CB*q21  + P1x*q22 + P1y*vswap(q22);
        v2f u22 = Q1x*q22 + Q1y*vswap(q22) + SB*q21;

        *(v2f*)((char*)H + wH00) = n11;
        *(v2f*)((char*)H + wH01) = n12;
        *(v2f*)((char*)H + wH10) = n21;
        *(v2f*)((char*)H + wH11) = n22;
        *(v2f*)((char*)V + wV00) = u11;
        *(v2f*)((char*)V + wV01) = u12;
        *(v2f*)((char*)V + wV10) = u21;
        *(v2f*)((char*)V + wV11) = u22;

        rr = (rr == 14) ? 0 : rr + 1;
        ++iter;
        if (chkcd == 1) {
            float off2 = n12.x*n12.x + n12.y*n12.y + n21.x*n21.x + n21.y*n21.y;
            if (!diagLane)
                off2 += n11.x*n11.x + n11.y*n11.y + n22.x*n22.x + n22.y*n22.y;
            #pragma unroll
            for (int m = 1; m < 64; m <<= 1) off2 += __shfl_xor(off2, m);
            __syncthreads();
            if (off2 < tol2 || iter >= MAXROUND) break;
            chkcd = CHKIV;
        } else { --chkcd; __syncthreads(); }
    }

    // ---- extraction: layout corresponds to pairing rr ----
    const int rrx = rr;
    if (t < 16) {
        int sd = slot_of(t, rrx);
        diagS[t] = (*(const v2f*)((const char*)H + laddr(sd, sd))).x;
    }
    __syncthreads();
    if (t == 0) {
        float best = diagS[0]; int bi_ = 0;
        for (int m = 1; m < 16; ++m) {
            float vv = diagS[m];
            if (vv < best) { best = vv; bi_ = m; }
        }
        midxS = bi_;
    }
    __syncthreads();
    {
        const int mi = midxS;
        const int sm = slot_of(mi, rrx);
        if (t < 16) psiS[t] = *(const v2f*)((const char*)V + laddr(t, sm));
    }
    __syncthreads();

    // ---- loss epilogue (R1-verbatim) ----
    float contrib = 0.f;
    if (t < 32) {
        float tr = 0.f, ti = 0.f;
        v2f psi[16];
        for (int jj = 0; jj < 16; ++jj) {
            psi[jj] = psiS[jj];
            tr += psi[jj].x; ti += psi[jj].y;
        }
        float zr = 0.f, zi = 0.f, z2r = 0.f, z2i = 0.f;
        for (int jj = 0; jj < 16; ++jj) {
            float2 cj  = cA [t*16 + jj];
            float2 c2j = cA2[t*16 + jj];
            zr  += cj.x*psi[jj].x  - cj.y*psi[jj].y;
            zi  += cj.x*psi[jj].y  + cj.y*psi[jj].x;
            z2r += c2j.x*psi[jj].x - c2j.y*psi[jj].y;
            z2i += c2j.x*psi[jj].y + c2j.y*psi[jj].x;
        }
        float pos = zr*tr + zi*ti;
        float e2  = z2r*tr + z2i*ti;
        float dx  = pos - xS[t];
        contrib = dx*dx + 0.1f*(e2 - pos*pos);
    }
    for (int off = 32; off > 0; off >>= 1)
        contrib += __shfl_down(contrib, off);
    if (t == 0) atomicAdd(out, contrib * (1.0f/(float)NS));
}

extern "C" void kernel_launch(void* const* d_in, const int* in_sizes, int n_in,
                              void* d_out, int out_size, void* d_ws, size_t ws_size,
                              hipStream_t stream)
{
    const float* A_real = (const float*)d_in[0];
    const float* A_imag = (const float*)d_in[1];
    const float* X      = (const float*)d_in[2];
    float* out = (float*)d_out;

    float2* S   = (float2*)d_ws;          // 32*256
    float2* W   = S  + DC*256;            // 32*256
    float2* cA  = W  + DC*256;            // 32*16
    float2* cA2 = cA + DC*16;             // 32*16
    (void)in_sizes; (void)n_in; (void)out_size; (void)ws_size;

    precompute_kernel<<<DC, 256, 0, stream>>>(A_real, A_imag, S, W, cA, cA2, out);
    energy_kernel<<<NS, 64, 0, stream>>>(X, S, W, cA, cA2, out);
}

// Round 11
// 160.213 us; speedup vs baseline: 1.0765x; 1.0765x over previous
//
#include <hip/hip_runtime.h>

#define NS 4096
#define DC 32
#define MAXROUND 210  // 14 sweeps cap
#define CHKIV 8       // gate check every 8 rounds

typedef float v2f __attribute__((ext_vector_type(2)));

static __device__ __forceinline__ v2f vswap(v2f b) {
    return __builtin_shufflevector(b, b, 1, 0);
}

// slot of matrix index r under round-rr pairing (pair k = {(rr+k)%15, (rr+15-k)%15}, p0=15)
static __device__ __forceinline__ int slot_of(int r, int rr) {
    if (r == 15) return 0;
    int m = r - rr; if (m < 0) m += 15;
    if (m == 0) return 1;
    return (m <= 7) ? 2*m : 31 - 2*m;
}
// tournament advance: content at slot s moves to pi_next(s) for the next round
static __device__ __forceinline__ int pi_next(int s) {
    if (s == 0) return 0;
    if (s == 2) return 1;
    if (!(s & 1)) return s - 2;
    return (s == 15) ? 14 : s + 2;
}
// bank-mix key: bijective over even rows AND over odd rows (kills a/a+4 alias)
static __device__ __forceinline__ int kmix(int sr) {
    return ((sr >> 1) ^ ((sr & 1) << 2)) & 7;
}
// byte address of (row sr, col-slot sc): XOR-swizzled, 16B pair-contiguous
static __device__ __forceinline__ int laddr(int sr, int sc) {
    return (sr << 7) | ((((sc >> 1) ^ kmix(sr)) & 7) << 4) | ((sc & 1) << 3);
}

// ---------------------------------------------------------------------------
// P1 (R1-verbatim) + d_out zeroing.
// ---------------------------------------------------------------------------
__global__ __launch_bounds__(256) void precompute_kernel(
    const float* __restrict__ Ar, const float* __restrict__ Ai,
    float2* __restrict__ S, float2* __restrict__ W,
    float2* __restrict__ cA, float2* __restrict__ cA2,
    float* __restrict__ out)
{
    const int d = blockIdx.x;
    const int t = threadIdx.x;
    if (d == 0 && t == 0) out[0] = 0.f;
    const int i = t >> 4, j = t & 15;
    __shared__ float ar[16][16], ai[16][16], a2r[16][16], a2i[16][16];
    ar[i][j] = Ar[d*256 + t];
    ai[i][j] = Ai[d*256 + t];
    __syncthreads();
    float a2re = 0.f, a2im = 0.f, wre = 0.f, wim = 0.f;
    for (int k = 0; k < 16; ++k) {
        float xr = ar[i][k], xi = ai[i][k];
        a2re += xr*ar[k][j] - xi*ai[k][j];
        a2im += xr*ai[k][j] + xi*ar[k][j];
        wre += xr*ar[j][k] + xi*ai[j][k];
        wim += xi*ar[j][k] - xr*ai[j][k];
    }
    S[d*256 + t] = make_float2(ar[i][j] + ar[j][i], ai[i][j] - ai[j][i]);
    W[d*256 + t] = make_float2(wre, wim);
    a2r[i][j] = a2re; a2i[i][j] = a2im;
    __syncthreads();
    if (t < 16) {
        float sr = 0.f, si = 0.f, s2r = 0.f, s2i = 0.f;
        for (int ii = 0; ii < 16; ++ii) {
            sr  += ar[ii][t];  si  += ai[ii][t];
            s2r += a2r[ii][t]; s2i += a2i[ii][t];
        }
        cA [d*16 + t] = make_float2(sr,  si);
        cA2[d*16 + t] = make_float2(s2r, s2i);
    }
}

// ---------------------------------------------------------------------------
// Slot-indexed quartet Jacobi: static XOR-swizzled addresses, b128 quartet
// reads, coef publication through a tiny LDS array (no shuffles in the loop).
// ---------------------------------------------------------------------------
__global__ __launch_bounds__(64) void energy_kernel(
    const float* __restrict__ X,
    const float2* __restrict__ S, const float2* __restrict__ W,
    const float2* __restrict__ cA, const float2* __restrict__ cA2,
    float* __restrict__ out)
{
    const int n = blockIdx.x;
    const int t = threadIdx.x;
    const int a = t >> 3, b = t & 7;

    __shared__ v2f    H[256], V[256];
    __shared__ float4 csco[8];     // raw (c, s, er, ei) per pair
    __shared__ float  xS[32];
    __shared__ float  diagS[16];
    __shared__ v2f    psiS[16];
    __shared__ int    midxS;

    const float* Xn = X + n*DC;
    if (t < 32) xS[t] = Xn[t];

    // ---- static addresses (loop-invariant) ----
    const int sr0 = 2*a, sr1 = 2*a + 1;     // H slot-rows == V matrix-rows
    const int sc0 = 2*b, sc1 = 2*b + 1;     // col slots
    const int rd0 = (sr0 << 7) | (((b ^ kmix(sr0)) & 7) << 4);  // 16B quartet row
    const int rd1 = (sr1 << 7) | (((b ^ kmix(sr1)) & 7) << 4);
    const int pr0 = pi_next(sr0), pr1 = pi_next(sr1);
    const int pc0 = pi_next(sc0), pc1 = pi_next(sc1);
    const int wH00 = laddr(pr0, pc0), wH01 = laddr(pr0, pc1);
    const int wH10 = laddr(pr1, pc0), wH11 = laddr(pr1, pc1);
    const int wV00 = laddr(sr0, pc0), wV01 = laddr(sr0, pc1);
    const int wV10 = laddr(sr1, pc0), wV11 = laddr(sr1, pc1);
    const bool diagLane = (a == b);

    // ---- build H (R1-exact arithmetic) into slot layout ----
    float tol2;
    {
        const int bi = t >> 2, bj = (t & 3) * 4, e0 = t * 4;
        v2f acc[4] = {{0.f,0.f},{0.f,0.f},{0.f,0.f},{0.f,0.f}};
        float sx2 = 0.f;
        for (int d = 0; d < DC; ++d) {
            float xd = Xn[d];
            sx2 += xd*xd;
            const float4* w4 = (const float4*)(W + d*256 + e0);
            const float4* s4 = (const float4*)(S + d*256 + e0);
            float4 wa = w4[0], wb = w4[1];
            float4 sa = s4[0], sb = s4[1];
            v2f xv = {xd, xd};
            acc[0] += (v2f){wa.x, wa.y} - xv * (v2f){sa.x, sa.y};
            acc[1] += (v2f){wa.z, wa.w} - xv * (v2f){sa.z, sa.w};
            acc[2] += (v2f){wb.x, wb.y} - xv * (v2f){sb.x, sb.y};
            acc[3] += (v2f){wb.z, wb.w} - xv * (v2f){sb.z, sb.w};
        }
        float sdiag = 0.5f*sx2 + 1e-5f;
        float nf = 0.f;
        const int sbi = slot_of(bi, 0);
        #pragma unroll
        for (int u = 0; u < 4; ++u) {
            int j = bj + u;
            v2f hv = 0.5f * acc[u];
            if (bi == j) hv.x += sdiag;
            nf += hv.x*hv.x + hv.y*hv.y;
            const int scj = slot_of(j, 0);
            *(v2f*)((char*)H + laddr(sbi, scj)) = hv;
            *(v2f*)((char*)V + laddr(bi,  scj)) =
                (bi == j) ? (v2f){1.f, 0.f} : (v2f){0.f, 0.f};
        }
        #pragma unroll
        for (int m = 1; m < 64; m <<= 1) nf += __shfl_xor(nf, m);
        tol2 = 1e-10f * nf;
    }
    __syncthreads();

    // ---- round loop ----
    int rr = 0, iter = 0, chkcd = CHKIV;
    for (;;) {
        // all lanes read their H and V quartets (independent of coefs)
        float4 f0 = *(const float4*)((const char*)H + rd0);
        float4 f1 = *(const float4*)((const char*)H + rd1);
        float4 g0 = *(const float4*)((const char*)V + rd0);
        float4 g1 = *(const float4*)((const char*)V + rd1);

        // diag lanes compute rotation from their own quartet and publish
        if (diagLane) {
            float av = f0.x, dv = f1.z;
            float ab2 = f0.z*f0.z + f0.w*f0.w;
            float c_, s_, er, ei;
            if (ab2 > 1e-60f) {
                float abr = __builtin_amdgcn_rsqf(ab2);
                er = f0.z * abr; ei = f0.w * abr;
                float tau = (dv - av) * (0.5f * abr);
                float den = fabsf(tau) + sqrtf(1.f + tau*tau);
                float tv = __builtin_amdgcn_rcpf(den);
                tv = (tau < 0.f) ? -tv : tv;
                c_ = __builtin_amdgcn_rsqf(1.f + tv*tv);
                s_ = tv * c_;
            } else { c_ = 1.f; s_ = 0.f; er = 1.f; ei = 0.f; }
            csco[a] = make_float4(c_, s_, er, ei);
        }
        __syncthreads();                      // coef visibility

        float4 fa = csco[a];
        float4 fb = csco[b];

        v2f h11 = {f0.x, f0.y}, h12 = {f0.z, f0.w};
        v2f h21 = {f1.x, f1.y}, h22 = {f1.z, f1.w};
        v2f q11 = {g0.x, g0.y}, q12 = {g0.z, g0.w};
        v2f q21 = {g1.x, g1.y}, q22 = {g1.z, g1.w};

        // rotation (R9/R10-verbatim math)
        const float cb = fb.x, sb = fb.y, ebx = fb.z, eby = fb.w;
        const float sbex = sb*ebx, sbey = sb*eby;
        const float cbex = cb*ebx, cbey = cb*eby;
        const v2f CB  = {cb, cb},      SB  = {sb, sb};
        const v2f P1x = {-sbex,-sbex}, P1y = {-sbey, sbey};
        const v2f Q1x = {cbex, cbex},  Q1y = {cbey,-cbey};
        const float ca = fa.x, sa = fa.y, eax = fa.z, eay = fa.w;
        const float saex = sa*eax, saey = sa*eay;
        const float caex = ca*eax, caey = ca*eay;
        const v2f CA  = {ca, ca},      SA  = {sa, sa};
        const v2f P2x = {-saex,-saex}, P2y = {saey,-saey};
        const v2f Q2x = {caex, caex},  Q2y = {-caey, caey};

        v2f t11 = CB*h11  + P1x*h12 + P1y*vswap(h12);
        v2f t12 = Q1x*h12 + Q1y*vswap(h12) + SB*h11;
        v2f t21 = CB*h21  + P1x*h22 + P1y*vswap(h22);
        v2f t22 = Q1x*h22 + Q1y*vswap(h22) + SB*h21;
        v2f n11 = CA*t11  + P2x*t21 + P2y*vswap(t21);
        v2f n12 = CA*t12  + P2x*t22 + P2y*vswap(t22);
        v2f n21 = Q2x*t21 + Q2y*vswap(t21) + SA*t11;
        v2f n22 = Q2x*t22 + Q2y*vswap(t22) + SA*t12;
        v2f u11 = CB*q11  + P1x*q12 + P1y*vswap(q12);
        v2f u12 = Q1x*q12 + Q1y*vswap(q12) + SB*q11;
        v2f u21 = CB*q21  + P1x*q22 + P1y*vswap(q22);
        v2f u22 = Q1x*q22 + Q1y*vswap(q22) + SB*q21;

        *(v2f*)((char*)H + wH00) = n11;
        *(v2f*)((char*)H + wH01) = n12;
        *(v2f*)((char*)H + wH10) = n21;
        *(v2f*)((char*)H + wH11) = n22;
        *(v2f*)((char*)V + wV00) = u11;
        *(v2f*)((char*)V + wV01) = u12;
        *(v2f*)((char*)V + wV10) = u21;
        *(v2f*)((char*)V + wV11) = u22;

        rr = (rr == 14) ? 0 : rr + 1;
        ++iter;
        if (chkcd == 1) {
            float off2 = n12.x*n12.x + n12.y*n12.y + n21.x*n21.x + n21.y*n21.y;
            if (!diagLane)
                off2 += n11.x*n11.x + n11.y*n11.y + n22.x*n22.x + n22.y*n22.y;
            #pragma unroll
            for (int m = 1; m < 64; m <<= 1) off2 += __shfl_xor(off2, m);
            __syncthreads();
            if (off2 < tol2 || iter >= MAXROUND) break;
            chkcd = CHKIV;
        } else { --chkcd; __syncthreads(); }
    }

    // ---- extraction: layout corresponds to pairing rr ----
    const int rrx = rr;
    if (t < 16) {
        int sd = slot_of(t, rrx);
        diagS[t] = (*(const v2f*)((const char*)H + laddr(sd, sd))).x;
    }
    __syncthreads();
    if (t == 0) {
        float best = diagS[0]; int bi_ = 0;
        for (int m = 1; m < 16; ++m) {
            float vv = diagS[m];
            if (vv < best) { best = vv; bi_ = m; }
        }
        midxS = bi_;
    }
    __syncthreads();
    {
        const int mi = midxS;
        const int sm = slot_of(mi, rrx);
        if (t < 16) psiS[t] = *(const v2f*)((const char*)V + laddr(t, sm));
    }
    __syncthreads();

    // ---- loss epilogue (R1-verbatim) ----
    float contrib = 0.f;
    if (t < 32) {
        float tr = 0.f, ti = 0.f;
        v2f psi[16];
        for (int jj = 0; jj < 16; ++jj) {
            psi[jj] = psiS[jj];
            tr += psi[jj].x; ti += psi[jj].y;
        }
        float zr = 0.f, zi = 0.f, z2r = 0.f, z2i = 0.f;
        for (int jj = 0; jj < 16; ++jj) {
            float2 cj  = cA [t*16 + jj];
            float2 c2j = cA2[t*16 + jj];
            zr  += cj.x*psi[jj].x  - cj.y*psi[jj].y;
            zi  += cj.x*psi[jj].y  + cj.y*psi[jj].x;
            z2r += c2j.x*psi[jj].x - c2j.y*psi[jj].y;
            z2i += c2j.x*psi[jj].y + c2j.y*psi[jj].x;
        }
        float pos = zr*tr + zi*ti;
        float e2  = z2r*tr + z2i*ti;
        float dx  = pos - xS[t];
        contrib = dx*dx + 0.1f*(e2 - pos*pos);
    }
    for (int off = 32; off > 0; off >>= 1)
        contrib += __shfl_down(contrib, off);
    if (t == 0) atomicAdd(out, contrib * (1.0f/(float)NS));
}

extern "C" void kernel_launch(void* const* d_in, const int* in_sizes, int n_in,
                              void* d_out, int out_size, void* d_ws, size_t ws_size,
                              hipStream_t stream)
{
    const float* A_real = (const float*)d_in[0];
    const float* A_imag = (const float*)d_in[1];
    const float* X      = (const float*)d_in[2];
    float* out = (float*)d_out;

    float2* S   = (float2*)d_ws;          // 32*256
    float2* W   = S  + DC*256;            // 32*256
    float2* cA  = W  + DC*256;            // 32*16
    float2* cA2 = cA + DC*16;             // 32*16
    (void)in_sizes; (void)n_in; (void)out_size; (void)ws_size;

    precompute_kernel<<<DC, 256, 0, stream>>>(A_real, A_imag, S, W, cA, cA2, out);
    energy_kernel<<<NS, 64, 0, stream>>>(X, S, W, cA, cA2, out);
}

// Round 13
// 158.102 us; speedup vs baseline: 1.0909x; 1.0134x over previous
//
#include <hip/hip_runtime.h>

#define NS 4096
#define DC 32
#define MAXROUND 210  // 14 sweeps cap
#define CHKIV 8       // gate check every 8 rounds

typedef float v2f __attribute__((ext_vector_type(2)));

// zero-instruction compiler memory fence: forbids reordering of LDS ops
// across it; HW per-wave DS FIFO supplies the actual ordering.
#define CFENCE() asm volatile("" ::: "memory")

static __device__ __forceinline__ v2f vswap(v2f b) {
    return __builtin_shufflevector(b, b, 1, 0);
}

// slot of matrix index r under round-rr pairing (pair k = {(rr+k)%15, (rr+15-k)%15}, p0=15)
static __device__ __forceinline__ int slot_of(int r, int rr) {
    if (r == 15) return 0;
    int m = r - rr; if (m < 0) m += 15;
    if (m == 0) return 1;
    return (m <= 7) ? 2*m : 31 - 2*m;
}
// tournament advance: content at slot s moves to pi_next(s) for the next round
static __device__ __forceinline__ int pi_next(int s) {
    if (s == 0) return 0;
    if (s == 2) return 1;
    if (!(s & 1)) return s - 2;
    return (s == 15) ? 14 : s + 2;
}
// bank-mix key: bijective over even rows AND over odd rows (kills a/a+4 alias)
static __device__ __forceinline__ int kmix(int sr) {
    return ((sr >> 1) ^ ((sr & 1) << 2)) & 7;
}
// byte address of (row sr, col-slot sc): XOR-swizzled, 16B pair-contiguous
static __device__ __forceinline__ int laddr(int sr, int sc) {
    return (sr << 7) | ((((sc >> 1) ^ kmix(sr)) & 7) << 4) | ((sc & 1) << 3);
}

// ---------------------------------------------------------------------------
// P1 (R1-verbatim) + d_out zeroing.
// ---------------------------------------------------------------------------
__global__ __launch_bounds__(256) void precompute_kernel(
    const float* __restrict__ Ar, const float* __restrict__ Ai,
    float2* __restrict__ S, float2* __restrict__ W,
    float2* __restrict__ cA, float2* __restrict__ cA2,
    float* __restrict__ out)
{
    const int d = blockIdx.x;
    const int t = threadIdx.x;
    if (d == 0 && t == 0) out[0] = 0.f;
    const int i = t >> 4, j = t & 15;
    __shared__ float ar[16][16], ai[16][16], a2r[16][16], a2i[16][16];
    ar[i][j] = Ar[d*256 + t];
    ai[i][j] = Ai[d*256 + t];
    __syncthreads();
    float a2re = 0.f, a2im = 0.f, wre = 0.f, wim = 0.f;
    for (int k = 0; k < 16; ++k) {
        float xr = ar[i][k], xi = ai[i][k];
        a2re += xr*ar[k][j] - xi*ai[k][j];
        a2im += xr*ai[k][j] + xi*ar[k][j];
        wre += xr*ar[j][k] + xi*ai[j][k];
        wim += xi*ar[j][k] - xr*ai[j][k];
    }
    S[d*256 + t] = make_float2(ar[i][j] + ar[j][i], ai[i][j] - ai[j][i]);
    W[d*256 + t] = make_float2(wre, wim);
    a2r[i][j] = a2re; a2i[i][j] = a2im;
    __syncthreads();
    if (t < 16) {
        float sr = 0.f, si = 0.f, s2r = 0.f, s2i = 0.f;
        for (int ii = 0; ii < 16; ++ii) {
            sr  += ar[ii][t];  si  += ai[ii][t];
            s2r += a2r[ii][t]; s2i += a2i[ii][t];
        }
        cA [d*16 + t] = make_float2(sr,  si);
        cA2[d*16 + t] = make_float2(s2r, s2i);
    }
}

// ---------------------------------------------------------------------------
// Slot-indexed quartet Jacobi: static XOR-swizzled addresses, b128 quartet
// reads, coef publication via LDS. Ordering inside the round loop is enforced
// with compiler-only fences (no s_waitcnt drains); the per-wave in-order DS
// pipeline guarantees read-after-write across lanes of the single wave.
// ---------------------------------------------------------------------------
__global__ __launch_bounds__(64) void energy_kernel(
    const float* __restrict__ X,
    const float2* __restrict__ S, const float2* __restrict__ W,
    const float2* __restrict__ cA, const float2* __restrict__ cA2,
    float* __restrict__ out)
{
    const int n = blockIdx.x;
    const int t = threadIdx.x;
    const int a = t >> 3, b = t & 7;

    __shared__ v2f    H[256], V[256];
    __shared__ float4 csco[8];     // raw (c, s, er, ei) per pair
    __shared__ float  xS[32];
    __shared__ float  diagS[16];
    __shared__ v2f    psiS[16];
    __shared__ int    midxS;

    const float* Xn = X + n*DC;
    if (t < 32) xS[t] = Xn[t];

    // ---- static addresses (loop-invariant) ----
    const int sr0 = 2*a, sr1 = 2*a + 1;     // H slot-rows == V matrix-rows
    const int sc0 = 2*b, sc1 = 2*b + 1;     // col slots
    const int rd0 = (sr0 << 7) | (((b ^ kmix(sr0)) & 7) << 4);  // 16B quartet row
    const int rd1 = (sr1 << 7) | (((b ^ kmix(sr1)) & 7) << 4);
    const int pr0 = pi_next(sr0), pr1 = pi_next(sr1);
    const int pc0 = pi_next(sc0), pc1 = pi_next(sc1);
    const int wH00 = laddr(pr0, pc0), wH01 = laddr(pr0, pc1);
    const int wH10 = laddr(pr1, pc0), wH11 = laddr(pr1, pc1);
    const int wV00 = laddr(sr0, pc0), wV01 = laddr(sr0, pc1);
    const int wV10 = laddr(sr1, pc0), wV11 = laddr(sr1, pc1);
    const bool diagLane = (a == b);

    // ---- build H (R1-exact arithmetic) into slot layout ----
    float tol2;
    {
        const int bi = t >> 2, bj = (t & 3) * 4, e0 = t * 4;
        v2f acc[4] = {{0.f,0.f},{0.f,0.f},{0.f,0.f},{0.f,0.f}};
        float sx2 = 0.f;
        for (int d = 0; d < DC; ++d) {
            float xd = Xn[d];
            sx2 += xd*xd;
            const float4* w4 = (const float4*)(W + d*256 + e0);
            const float4* s4 = (const float4*)(S + d*256 + e0);
            float4 wa = w4[0], wb = w4[1];
            float4 sa = s4[0], sb = s4[1];
            v2f xv = {xd, xd};
            acc[0] += (v2f){wa.x, wa.y} - xv * (v2f){sa.x, sa.y};
            acc[1] += (v2f){wa.z, wa.w} - xv * (v2f){sa.z, sa.w};
            acc[2] += (v2f){wb.x, wb.y} - xv * (v2f){sb.x, sb.y};
            acc[3] += (v2f){wb.z, wb.w} - xv * (v2f){sb.z, sb.w};
        }
        float sdiag = 0.5f*sx2 + 1e-5f;
        float nf = 0.f;
        const int sbi = slot_of(bi, 0);
        #pragma unroll
        for (int u = 0; u < 4; ++u) {
            int j = bj + u;
            v2f hv = 0.5f * acc[u];
            if (bi == j) hv.x += sdiag;
            nf += hv.x*hv.x + hv.y*hv.y;
            const int scj = slot_of(j, 0);
            *(v2f*)((char*)H + laddr(sbi, scj)) = hv;
            *(v2f*)((char*)V + laddr(bi,  scj)) =
                (bi == j) ? (v2f){1.f, 0.f} : (v2f){0.f, 0.f};
        }
        #pragma unroll
        for (int m = 1; m < 64; m <<= 1) nf += __shfl_xor(nf, m);
        tol2 = 1e-10f * nf;
    }
    __syncthreads();   // once: build -> loop

    // ---- round loop (compiler fences only; HW DS FIFO orders the data) ----
    int rr = 0, iter = 0, chkcd = CHKIV;
    for (;;) {
        float4 f0 = *(const float4*)((const char*)H + rd0);
        float4 f1 = *(const float4*)((const char*)H + rd1);
        float4 g0 = *(const float4*)((const char*)V + rd0);
        float4 g1 = *(const float4*)((const char*)V + rd1);

        // diag lanes compute rotation from their own quartet and publish
        if (diagLane) {
            float av = f0.x, dv = f1.z;
            float ab2 = f0.z*f0.z + f0.w*f0.w;
            float c_, s_, er, ei;
            if (ab2 > 1e-60f) {
                float abr = __builtin_amdgcn_rsqf(ab2);
                er = f0.z * abr; ei = f0.w * abr;
                float tau = (dv - av) * (0.5f * abr);
                float den = fabsf(tau) + sqrtf(1.f + tau*tau);
                float tv = __builtin_amdgcn_rcpf(den);
                tv = (tau < 0.f) ? -tv : tv;
                c_ = __builtin_amdgcn_rsqf(1.f + tv*tv);
                s_ = tv * c_;
            } else { c_ = 1.f; s_ = 0.f; er = 1.f; ei = 0.f; }
            csco[a] = make_float4(c_, s_, er, ei);
        }
        CFENCE();                 // csco write ordered before csco reads

        float4 fa = csco[a];
        float4 fb = csco[b];

        v2f h11 = {f0.x, f0.y}, h12 = {f0.z, f0.w};
        v2f h21 = {f1.x, f1.y}, h22 = {f1.z, f1.w};
        v2f q11 = {g0.x, g0.y}, q12 = {g0.z, g0.w};
        v2f q21 = {g1.x, g1.y}, q22 = {g1.z, g1.w};

        // rotation (R9/R10/R11-verbatim math)
        const float cb = fb.x, sb = fb.y, ebx = fb.z, eby = fb.w;
        const float sbex = sb*ebx, sbey = sb*eby;
        const float cbex = cb*ebx, cbey = cb*eby;
        const v2f CB  = {cb, cb},      SB  = {sb, sb};
        const v2f P1x = {-sbex,-sbex}, P1y = {-sbey, sbey};
        const v2f Q1x = {cbex, cbex},  Q1y = {cbey,-cbey};
        const float ca = fa.x, sa = fa.y, eax = fa.z, eay = fa.w;
        const float saex = sa*eax, saey = sa*eay;
        const float caex = ca*eax, caey = ca*eay;
        const v2f CA  = {ca, ca},      SA  = {sa, sa};
        const v2f P2x = {-saex,-saex}, P2y = {saey,-saey};
        const v2f Q2x = {caex, caex},  Q2y = {-caey, caey};

        v2f t11 = CB*h11  + P1x*h12 + P1y*vswap(h12);
        v2f t12 = Q1x*h12 + Q1y*vswap(h12) + SB*h11;
        v2f t21 = CB*h21  + P1x*h22 + P1y*vswap(h22);
        v2f t22 = Q1x*h22 + Q1y*vswap(h22) + SB*h21;
        v2f n11 = CA*t11  + P2x*t21 + P2y*vswap(t21);
        v2f n12 = CA*t12  + P2x*t22 + P2y*vswap(t22);
        v2f n21 = Q2x*t21 + Q2y*vswap(t21) + SA*t11;
        v2f n22 = Q2x*t22 + Q2y*vswap(t22) + SA*t12;
        v2f u11 = CB*q11  + P1x*q12 + P1y*vswap(q12);
        v2f u12 = Q1x*q12 + Q1y*vswap(q12) + SB*q11;
        v2f u21 = CB*q21  + P1x*q22 + P1y*vswap(q22);
        v2f u22 = Q1x*q22 + Q1y*vswap(q22) + SB*q21;

        *(v2f*)((char*)H + wH00) = n11;
        *(v2f*)((char*)H + wH01) = n12;
        *(v2f*)((char*)H + wH10) = n21;
        *(v2f*)((char*)H + wH11) = n22;
        *(v2f*)((char*)V + wV00) = u11;
        *(v2f*)((char*)V + wV01) = u12;
        *(v2f*)((char*)V + wV10) = u21;
        *(v2f*)((char*)V + wV11) = u22;
        CFENCE();                 // round stores ordered before next reads

        rr = (rr == 14) ? 0 : rr + 1;
        ++iter;
        if (chkcd == 1) {
            float off2 = n12.x*n12.x + n12.y*n12.y + n21.x*n21.x + n21.y*n21.y;
            if (!diagLane)
                off2 += n11.x*n11.x + n11.y*n11.y + n22.x*n22.x + n22.y*n22.y;
            #pragma unroll
            for (int m = 1; m < 64; m <<= 1) off2 += __shfl_xor(off2, m);
            if (off2 < tol2 || iter >= MAXROUND) break;
            chkcd = CHKIV;
        } else { --chkcd; }
    }
    __syncthreads();   // once: loop -> extraction

    // ---- extraction: layout corresponds to pairing rr ----
    const int rrx = rr;
    if (t < 16) {
        int sd = slot_of(t, rrx);
        diagS[t] = (*(const v2f*)((const char*)H + laddr(sd, sd))).x;
    }
    __syncthreads();
    if (t == 0) {
        float best = diagS[0]; int bi_ = 0;
        for (int m = 1; m < 16; ++m) {
            float vv = diagS[m];
            if (vv < best) { best = vv; bi_ = m; }
        }
        midxS = bi_;
    }
    __syncthreads();
    {
        const int mi = midxS;
        const int sm = slot_of(mi, rrx);
        if (t < 16) psiS[t] = *(const v2f*)((const char*)V + laddr(t, sm));
    }
    __syncthreads();

    // ---- loss epilogue (R1-verbatim) ----
    float contrib = 0.f;
    if (t < 32) {
        float tr = 0.f, ti = 0.f;
        v2f psi[16];
        for (int jj = 0; jj < 16; ++jj) {
            psi[jj] = psiS[jj];
            tr += psi[jj].x; ti += psi[jj].y;
        }
        float zr = 0.f, zi = 0.f, z2r = 0.f, z2i = 0.f;
        for (int jj = 0; jj < 16; ++jj) {
            float2 cj  = cA [t*16 + jj];
            float2 c2j = cA2[t*16 + jj];
            zr  += cj.x*psi[jj].x  - cj.y*psi[jj].y;
            zi  += cj.x*psi[jj].y  + cj.y*psi[jj].x;
            z2r += c2j.x*psi[jj].x - c2j.y*psi[jj].y;
            z2i += c2j.x*psi[jj].y + c2j.y*psi[jj].x;
        }
        float pos = zr*tr + zi*ti;
        float e2  = z2r*tr + z2i*ti;
        float dx  = pos - xS[t];
        contrib = dx*dx + 0.1f*(e2 - pos*pos);
    }
    for (int off = 32; off > 0; off >>= 1)
        contrib += __shfl_down(contrib, off);
    if (t == 0) atomicAdd(out, contrib * (1.0f/(float)NS));
}

extern "C" void kernel_launch(void* const* d_in, const int* in_sizes, int n_in,
                              void* d_out, int out_size, void* d_ws, size_t ws_size,
                              hipStream_t stream)
{
    const float* A_real = (const float*)d_in[0];
    const float* A_imag = (const float*)d_in[1];
    const float* X      = (const float*)d_in[2];
    float* out = (float*)d_out;

    float2* S   = (float2*)d_ws;          // 32*256
    float2* W   = S  + DC*256;            // 32*256
    float2* cA  = W  + DC*256;            // 32*16
    float2* cA2 = cA + DC*16;             // 32*16
    (void)in_sizes; (void)n_in; (void)out_size; (void)ws_size;

    precompute_kernel<<<DC, 256, 0, stream>>>(A_real, A_imag, S, W, cA, cA2, out);
    energy_kernel<<<NS, 64, 0, stream>>>(X, S, W, cA, cA2, out);
}